// Round 11
// baseline (94.776 us; speedup 1.0000x reference)
//
#include <hip/hip_runtime.h>
#include <math.h>

#define DIM   2048
#define NEXP  64
#define TOPK  8
#define ROWS  32           // rows per block in GEMM; 8 waves, split-K-8
#define NT    512
#define NBLK  512          // M / ROWS

typedef __attribute__((ext_vector_type(8)))  short bf16x8;
typedef __attribute__((ext_vector_type(16))) float f32x16;

#define MFMA(A, B, C) __builtin_amdgcn_mfma_f32_32x32x16_bf16(A, B, C, 0, 0, 0)
#define AS_BF(v) (*(const bf16x8*)&(v))

typedef __attribute__((address_space(3))) unsigned int       lds_uint;
typedef __attribute__((address_space(1))) const unsigned int glb_uint;

#define STR2(x) #x
#define STR(x) STR2(x)
#define GL16(dst, p, off) \
    asm volatile("global_load_dwordx4 %0, %1, off offset:" STR(off) \
                 : "=v"(dst) : "v"(p) : "memory")

__device__ inline unsigned int bfpack(float a, float b) {
    unsigned int ua = __float_as_uint(a), ub = __float_as_uint(b);
    unsigned int lo = (ua + 0x7FFFu + ((ua >> 16) & 1u)) >> 16;
    unsigned int hi = (ub + 0x7FFFu + ((ub >> 16) & 1u)) & 0xFFFF0000u;
    return hi | lo;
}
__device__ inline void split2pair(float a, float b, unsigned int& h, unsigned int& m) {
    h = bfpack(a, b);
    float ra = a - __uint_as_float(h << 16);
    float rb = b - __uint_as_float(h & 0xFFFF0000u);
    m = bfpack(ra, rb);
}

// w[e][k] f32 -> byte = wv*65536 + t*4096 + (eh*2+term)*1024 + (kh*32+le)*16
__global__ __launch_bounds__(256) void prep_kernel(const float* __restrict__ w,
                                                   unsigned int* __restrict__ wpack) {
    const int u = blockIdx.x * 256 + threadIdx.x;   // 0..16383
    const int e = u >> 8, k8 = u & 255;
    const float4 v0 = *(const float4*)(w + (size_t)e * DIM + k8 * 8);
    const float4 v1 = *(const float4*)(w + (size_t)e * DIM + k8 * 8 + 4);
    unsigned int h[4], m[4];
    split2pair(v0.x, v0.y, h[0], m[0]);
    split2pair(v0.z, v0.w, h[1], m[1]);
    split2pair(v1.x, v1.y, h[2], m[2]);
    split2pair(v1.z, v1.w, h[3], m[3]);
    const int wv = k8 >> 5, t = (k8 >> 1) & 15, kh = k8 & 1;
    const int eh = e >> 5, le = e & 31;
    char* base = (char*)wpack + (size_t)wv * 65536 + t * 4096
               + (eh * 2) * 1024 + (kh * 32 + le) * 16;
    *(uint4*)(base)        = (uint4){h[0], h[1], h[2], h[3]};
    *(uint4*)(base + 1024) = (uint4){m[0], m[1], m[2], m[3]};
}

// ---------------- Kernel A: GEMM only -> split-K partials in d_ws ----------------
__global__ __launch_bounds__(NT) void gemm_kernel(
    const float* __restrict__ x,
    const unsigned int* __restrict__ wpack,
    float* __restrict__ part,    // [8][M][64] f32
    int M)
{
    __shared__ __align__(16) float xtile[8192];   // 32 KB: 8 waves x 2 slots x 512 floats

    const int tid  = threadIdx.x;
    const int bid  = blockIdx.x;
    const int swz  = (bid & 7) * (NBLK / 8) + (bid >> 3);    // bijective XCD swizzle
    const int row0 = swz * ROWS;

    const int wv   = tid >> 6;      // K-slice (split-K-8)
    const int lane = tid & 63;
    const int lr   = lane & 31;
    const int kh   = lane >> 5;

    const float* xg0 = x + (size_t)(row0 +  0 + (lane & 15)) * DIM + wv * 256 + (lane >> 4) * 4;
    const float* xg1 = x + (size_t)(row0 + 16 + (lane & 15)) * DIM + wv * 256 + (lane >> 4) * 4;
    const char* wsl = (const char*)wpack + (size_t)wv * 65536 + lane * 16;
    float* xtb = xtile + wv * 1024;
    const int rdo = (lr >> 4) * 256 + kh * 128 + (lr & 15) * 4;

    f32x16 acc0 = {}, acc1 = {};
    uint4 wH0_0, wM0_0, wH1_0, wM1_0;
    uint4 wH0_1, wM0_1, wH1_1, wM1_1;

#define ISSUE(s, tt) do { \
        __builtin_amdgcn_global_load_lds((glb_uint*)(const void*)(xg0 + (tt) * 16), \
                                         (lds_uint*)(void*)(xtb + (s) * 512), 16, 0, 0); \
        __builtin_amdgcn_global_load_lds((glb_uint*)(const void*)(xg1 + (tt) * 16), \
                                         (lds_uint*)(void*)(xtb + (s) * 512 + 256), 16, 0, 0); \
        asm volatile("" ::: "memory"); \
        { const char* p_ = wsl + (tt) * 4096; \
          GL16(wH0_##s, p_, 0);    GL16(wM0_##s, p_, 1024); \
          GL16(wH1_##s, p_, 2048); GL16(wM1_##s, p_, 3072); } \
    } while (0)

#define DOSPLIT(vlo, vhi, hv, mv) do { \
        unsigned int h_[4], m_[4]; \
        split2pair((vlo).x, (vlo).y, h_[0], m_[0]); \
        split2pair((vlo).z, (vlo).w, h_[1], m_[1]); \
        split2pair((vhi).x, (vhi).y, h_[2], m_[2]); \
        split2pair((vhi).z, (vhi).w, h_[3], m_[3]); \
        hv = (uint4){h_[0], h_[1], h_[2], h_[3]}; \
        mv = (uint4){m_[0], m_[1], m_[2], m_[3]}; \
    } while (0)

#define KITER(s, WAITLIT, ISS) do { \
        asm volatile("s_waitcnt vmcnt(" WAITLIT ")" ::: "memory"); \
        __builtin_amdgcn_sched_barrier(0); \
        float4 alo_ = *(const float4*)(xtb + (s) * 512 + rdo); \
        float4 ahi_ = *(const float4*)(xtb + (s) * 512 + rdo + 64); \
        uint4 ah_, am_; \
        DOSPLIT(alo_, ahi_, ah_, am_); \
        acc0 = MFMA(AS_BF(ah_), AS_BF(wH0_##s), acc0); \
        acc0 = MFMA(AS_BF(am_), AS_BF(wH0_##s), acc0); \
        acc0 = MFMA(AS_BF(ah_), AS_BF(wM0_##s), acc0); \
        acc1 = MFMA(AS_BF(ah_), AS_BF(wH1_##s), acc1); \
        acc1 = MFMA(AS_BF(am_), AS_BF(wH1_##s), acc1); \
        acc1 = MFMA(AS_BF(ah_), AS_BF(wM1_##s), acc1); \
        __builtin_amdgcn_sched_barrier(0); \
        ISS; \
    } while (0)

    ISSUE(0, 0); ISSUE(1, 1);
    KITER(0, "6", ISSUE(0, 2));
    KITER(1, "6", ISSUE(1, 3));
    KITER(0, "6", ISSUE(0, 4));
    KITER(1, "6", ISSUE(1, 5));
    KITER(0, "6", ISSUE(0, 6));
    KITER(1, "6", ISSUE(1, 7));
    KITER(0, "6", ISSUE(0, 8));
    KITER(1, "6", ISSUE(1, 9));
    KITER(0, "6", ISSUE(0, 10));
    KITER(1, "6", ISSUE(1, 11));
    KITER(0, "6", ISSUE(0, 12));
    KITER(1, "6", ISSUE(1, 13));
    KITER(0, "6", ISSUE(0, 14));
    KITER(1, "6", ISSUE(1, 15));
    KITER(0, "6", );
    KITER(1, "0", );
#undef KITER
#undef DOSPLIT
#undef ISSUE

    // coalesced partial store: part[wv][row][e]
    #pragma unroll
    for (int r = 0; r < 16; ++r) {
        const int rr = (r & 3) + 8 * (r >> 2) + 4 * kh;   // verified C-layout (m74/m101)
        float* p = part + ((size_t)wv * M + (row0 + rr)) * 64;
        p[lr]      = acc0[r];
        p[lr + 32] = acc1[r];
    }
}

// ---------------- Kernel B: reduce slices + top-k + softmax + histogram ----------------
__global__ __launch_bounds__(256) void topk_kernel(
    const float* __restrict__ part,   // [8][M][64]
    const float* __restrict__ bias,
    float* __restrict__ out,          // [M*8] scores | [M*8] idx(f32) | [64] counts
    int* __restrict__ histws,         // [512][64]
    int M)
{
    __shared__ int hist[NEXP];
    const int tid = threadIdx.x, bid = blockIdx.x;
    const int wv = tid >> 6, lane = tid & 63;
    if (tid < NEXP) hist[tid] = 0;
    __syncthreads();

    float* out_scores = out;
    float* out_idx    = out + (size_t)M * TOPK;
    const int rbase = bid * 32 + wv * 8;

    for (int i = 0; i < 8; ++i) {
        const int row = rbase + i;
        float vm = bias[lane];
        #pragma unroll
        for (int s = 0; s < 8; ++s) vm += part[((size_t)s * M + row) * 64 + lane];

        float vals[TOPK];
        int   ids[TOPK];
        #pragma unroll
        for (int k = 0; k < TOPK; ++k) {
            float mv = vm;
            int   mi = lane;
            #pragma unroll
            for (int off = 32; off > 0; off >>= 1) {
                float ov = __shfl_xor(mv, off);
                int   oi = __shfl_xor(mi, off);
                if (ov > mv || (ov == mv && oi < mi)) { mv = ov; mi = oi; }
            }
            vals[k] = mv; ids[k] = mi;
            if (lane == mi) { vm = -INFINITY; atomicAdd(&hist[mi], 1); }
        }
        if (lane == 0) {
            const float m = vals[0];
            float e[TOPK];
            float ssum = 0.f;
            #pragma unroll
            for (int k = 0; k < TOPK; ++k) { e[k] = expf(vals[k] - m); ssum += e[k]; }
            const float inv = 1.0f / ssum;
            const size_t base = (size_t)row * TOPK;
            #pragma unroll
            for (int k = 0; k < TOPK; ++k) {
                out_scores[base + k] = e[k] * inv;
                out_idx[base + k]    = (float)ids[k];
            }
        }
    }

    __syncthreads();
    if (tid < NEXP) histws[bid * NEXP + tid] = hist[tid];
}

__global__ __launch_bounds__(512) void reduce_kernel(const int* __restrict__ histws,
                                                     float* __restrict__ counts) {
    __shared__ int partl[8][NEXP];
    const int t = threadIdx.x;
    const int e = t & 63, c = t >> 6;
    int sm = 0;
    for (int b = c; b < NBLK; b += 8) sm += histws[b * NEXP + e];
    partl[c][e] = sm;
    __syncthreads();
    if (t < NEXP) {
        int tot = 0;
        #pragma unroll
        for (int i = 0; i < 8; ++i) tot += partl[i][t];
        counts[t] = (float)tot;
    }
}

extern "C" void kernel_launch(void* const* d_in, const int* in_sizes, int n_in,
                              void* d_out, int out_size, void* d_ws, size_t ws_size,
                              hipStream_t stream) {
    const float* x    = (const float*)d_in[0];
    const float* w    = (const float*)d_in[1];
    const float* bias = (const float*)d_in[2];
    float* out = (float*)d_out;
    const int M = in_sizes[0] / DIM;   // 16384 rows

    // ws layout: wpack 512KB @0 | histws 128KB @1MB | partials 32MB @2MB
    unsigned int* wpack = (unsigned int*)d_ws;
    int*   histws   = (int*)((char*)d_ws + (1u << 20));
    float* partials = (float*)((char*)d_ws + (2u << 20));
    float* out_counts = out + (size_t)2 * M * TOPK;

    prep_kernel<<<64, 256, 0, stream>>>(w, wpack);
    gemm_kernel<<<NBLK, NT, 0, stream>>>(x, wpack, partials, M);
    topk_kernel<<<M / 32, 256, 0, stream>>>(partials, bias, out, histws, M);
    reduce_kernel<<<1, 512, 0, stream>>>(histws, out_counts);
}

// Round 12
// 84.050 us; speedup vs baseline: 1.1276x; 1.1276x over previous
//
#include <hip/hip_runtime.h>
#include <math.h>

#define DIM   2048
#define NEXP  64
#define TOPK  8
#define BM    64           // rows per block; 8 waves, split-K-8, each wave all 64 rows
#define NT    512
#define NBLK  256          // M / BM

typedef __attribute__((ext_vector_type(8)))  short bf16x8;
typedef __attribute__((ext_vector_type(16))) float f32x16;

#define MFMA(A, B, C) __builtin_amdgcn_mfma_f32_32x32x16_bf16(A, B, C, 0, 0, 0)
#define AS_BF(v) (*(const bf16x8*)&(v))

typedef __attribute__((address_space(3))) unsigned int       lds_uint;
typedef __attribute__((address_space(1))) const unsigned int glb_uint;

#define STR2(x) #x
#define STR(x) STR2(x)
#define GL16(dst, p, off) \
    asm volatile("global_load_dwordx4 %0, %1, off offset:" STR(off) \
                 : "=v"(dst) : "v"(p) : "memory")

__device__ inline unsigned int bfpack(float a, float b) {
    unsigned int ua = __float_as_uint(a), ub = __float_as_uint(b);
    unsigned int lo = (ua + 0x7FFFu + ((ua >> 16) & 1u)) >> 16;
    unsigned int hi = (ub + 0x7FFFu + ((ub >> 16) & 1u)) & 0xFFFF0000u;
    return hi | lo;
}
__device__ inline void split2pair(float a, float b, unsigned int& h, unsigned int& m) {
    h = bfpack(a, b);
    float ra = a - __uint_as_float(h << 16);
    float rb = b - __uint_as_float(h & 0xFFFF0000u);
    m = bfpack(ra, rb);
}

// w[e][k] f32 -> byte = wv*65536 + t*4096 + (eh*2+term)*1024 + (kh*32+le)*16
__global__ __launch_bounds__(256) void prep_kernel(const float* __restrict__ w,
                                                   unsigned int* __restrict__ wpack) {
    const int u = blockIdx.x * 256 + threadIdx.x;   // 0..16383
    const int e = u >> 8, k8 = u & 255;
    const float4 v0 = *(const float4*)(w + (size_t)e * DIM + k8 * 8);
    const float4 v1 = *(const float4*)(w + (size_t)e * DIM + k8 * 8 + 4);
    unsigned int h[4], m[4];
    split2pair(v0.x, v0.y, h[0], m[0]);
    split2pair(v0.z, v0.w, h[1], m[1]);
    split2pair(v1.x, v1.y, h[2], m[2]);
    split2pair(v1.z, v1.w, h[3], m[3]);
    const int wv = k8 >> 5, t = (k8 >> 1) & 15, kh = k8 & 1;
    const int eh = e >> 5, le = e & 31;
    char* base = (char*)wpack + (size_t)wv * 65536 + t * 4096
               + (eh * 2) * 1024 + (kh * 32 + le) * 16;
    *(uint4*)(base)        = (uint4){h[0], h[1], h[2], h[3]};
    *(uint4*)(base + 1024) = (uint4){m[0], m[1], m[2], m[3]};
}

__global__ __launch_bounds__(NT, 2) void router_kernel(
    const float* __restrict__ x,
    const unsigned int* __restrict__ wpack,
    const float* __restrict__ bias,
    float* __restrict__ out,     // [M*8] scores | [M*8] idx(f32) | [64] counts(f32)
    int* __restrict__ histws,    // [NBLK][64]
    int M)
{
    // xtile: 8 waves x 2 slots x 1024 floats (4 KB/slot) = 64 KB; lg[64][66] aliases it
    __shared__ __align__(16) float xtile[16384];
    __shared__ int hist[NEXP];

    const int tid  = threadIdx.x;
    const int bid  = blockIdx.x;
    const int swz  = (bid & 7) * (NBLK / 8) + (bid >> 3);    // bijective XCD swizzle
    const int row0 = swz * BM;
    if (tid < NEXP) hist[tid] = 0;

    const int wv   = tid >> 6;      // K-slice (split-K-8)
    const int lane = tid & 63;
    const int lr   = lane & 31;
    const int kh   = lane >> 5;

    // x DMA sources: 4 per tile, half rg (32 rows) x sub d (16 rows)
    //   lane -> row = rg*32 + d*16 + (lane&15), granule q = lane>>4 (R11 mapping, 0 conflicts)
    const float* xg00 = x + (size_t)(row0 +  0 + (lane & 15)) * DIM + wv * 256 + (lane >> 4) * 4;
    const float* xg01 = x + (size_t)(row0 + 16 + (lane & 15)) * DIM + wv * 256 + (lane >> 4) * 4;
    const float* xg10 = x + (size_t)(row0 + 32 + (lane & 15)) * DIM + wv * 256 + (lane >> 4) * 4;
    const float* xg11 = x + (size_t)(row0 + 48 + (lane & 15)) * DIM + wv * 256 + (lane >> 4) * 4;
    const char* wsl = (const char*)wpack + (size_t)wv * 65536 + lane * 16;
    float* xtb = xtile + wv * 2048;       // 2 slots x 1024 floats
    const int rdo = (lr >> 4) * 256 + kh * 128 + (lr & 15) * 4;   // floats, within 512-float half

    f32x16 acc00 = {}, acc01 = {}, acc10 = {}, acc11 = {};
    uint4 wH0_0, wM0_0, wH1_0, wM1_0;
    uint4 wH0_1, wM0_1, wH1_1, wM1_1;

#define ISSUE(s, tt) do { \
        float* d_ = xtb + (s) * 1024; \
        __builtin_amdgcn_global_load_lds((glb_uint*)(const void*)(xg00 + (tt) * 16), \
                                         (lds_uint*)(void*)(d_), 16, 0, 0); \
        __builtin_amdgcn_global_load_lds((glb_uint*)(const void*)(xg01 + (tt) * 16), \
                                         (lds_uint*)(void*)(d_ + 256), 16, 0, 0); \
        __builtin_amdgcn_global_load_lds((glb_uint*)(const void*)(xg10 + (tt) * 16), \
                                         (lds_uint*)(void*)(d_ + 512), 16, 0, 0); \
        __builtin_amdgcn_global_load_lds((glb_uint*)(const void*)(xg11 + (tt) * 16), \
                                         (lds_uint*)(void*)(d_ + 768), 16, 0, 0); \
        asm volatile("" ::: "memory"); \
        { const char* p_ = wsl + (tt) * 4096; \
          GL16(wH0_##s, p_, 0);    GL16(wM0_##s, p_, 1024); \
          GL16(wH1_##s, p_, 2048); GL16(wM1_##s, p_, 3072); } \
    } while (0)

#define DOSPLIT(vlo, vhi, hv, mv) do { \
        unsigned int h_[4], m_[4]; \
        split2pair((vlo).x, (vlo).y, h_[0], m_[0]); \
        split2pair((vlo).z, (vlo).w, h_[1], m_[1]); \
        split2pair((vhi).x, (vhi).y, h_[2], m_[2]); \
        split2pair((vhi).z, (vhi).w, h_[3], m_[3]); \
        hv = (uint4){h_[0], h_[1], h_[2], h_[3]}; \
        mv = (uint4){m_[0], m_[1], m_[2], m_[3]}; \
    } while (0)

#define KITER(s, WAITLIT, ISS) do { \
        asm volatile("s_waitcnt vmcnt(" WAITLIT ")" ::: "memory"); \
        __builtin_amdgcn_sched_barrier(0); \
        float4 alo0_ = *(const float4*)(xtb + (s) * 1024 + rdo); \
        float4 ahi0_ = *(const float4*)(xtb + (s) * 1024 + rdo + 64); \
        float4 alo1_ = *(const float4*)(xtb + (s) * 1024 + 512 + rdo); \
        float4 ahi1_ = *(const float4*)(xtb + (s) * 1024 + 512 + rdo + 64); \
        uint4 ah_, am_; \
        DOSPLIT(alo0_, ahi0_, ah_, am_); \
        acc00 = MFMA(AS_BF(ah_), AS_BF(wH0_##s), acc00); \
        acc00 = MFMA(AS_BF(am_), AS_BF(wH0_##s), acc00); \
        acc00 = MFMA(AS_BF(ah_), AS_BF(wM0_##s), acc00); \
        acc01 = MFMA(AS_BF(ah_), AS_BF(wH1_##s), acc01); \
        acc01 = MFMA(AS_BF(am_), AS_BF(wH1_##s), acc01); \
        acc01 = MFMA(AS_BF(ah_), AS_BF(wM1_##s), acc01); \
        DOSPLIT(alo1_, ahi1_, ah_, am_); \
        acc10 = MFMA(AS_BF(ah_), AS_BF(wH0_##s), acc10); \
        acc10 = MFMA(AS_BF(am_), AS_BF(wH0_##s), acc10); \
        acc10 = MFMA(AS_BF(ah_), AS_BF(wM0_##s), acc10); \
        acc11 = MFMA(AS_BF(ah_), AS_BF(wH1_##s), acc11); \
        acc11 = MFMA(AS_BF(am_), AS_BF(wH1_##s), acc11); \
        acc11 = MFMA(AS_BF(ah_), AS_BF(wM1_##s), acc11); \
        __builtin_amdgcn_sched_barrier(0); \
        ISS; \
    } while (0)

    ISSUE(0, 0); ISSUE(1, 1);
    KITER(0, "8", ISSUE(0, 2));
    KITER(1, "8", ISSUE(1, 3));
    KITER(0, "8", ISSUE(0, 4));
    KITER(1, "8", ISSUE(1, 5));
    KITER(0, "8", ISSUE(0, 6));
    KITER(1, "8", ISSUE(1, 7));
    KITER(0, "8", ISSUE(0, 8));
    KITER(1, "8", ISSUE(1, 9));
    KITER(0, "8", ISSUE(0, 10));
    KITER(1, "8", ISSUE(1, 11));
    KITER(0, "8", ISSUE(0, 12));
    KITER(1, "8", ISSUE(1, 13));
    KITER(0, "8", ISSUE(0, 14));
    KITER(1, "8", ISSUE(1, 15));
    KITER(0, "8", );
    KITER(1, "0", );
#undef KITER
#undef DOSPLIT
#undef ISSUE

    __syncthreads();

    // ---- split-K-8 reduce in LDS: 8 serialized wave-stages into lg[64][66] ----
    float* lg = xtile;   // 64*66*4 = 16.9 KB, aliases xtile
    for (int p = 0; p < 8; ++p) {
        if (wv == p) {
            #pragma unroll
            for (int r = 0; r < 16; ++r) {
                const int rr = (r & 3) + 8 * (r >> 2) + 4 * kh;   // verified C-layout (m74/m101)
                if (p == 0) {
                    lg[rr * 66 + lr]             = acc00[r];
                    lg[rr * 66 + 32 + lr]        = acc01[r];
                    lg[(32 + rr) * 66 + lr]      = acc10[r];
                    lg[(32 + rr) * 66 + 32 + lr] = acc11[r];
                } else {
                    lg[rr * 66 + lr]             += acc00[r];
                    lg[rr * 66 + 32 + lr]        += acc01[r];
                    lg[(32 + rr) * 66 + lr]      += acc10[r];
                    lg[(32 + rr) * 66 + 32 + lr] += acc11[r];
                }
            }
        }
        __syncthreads();
    }

    // ---- top-k + softmax + histogram (verified epilogue); wave wv: rows wv*8..+8 ----
    float* out_scores = out;
    float* out_idx    = out + (size_t)M * TOPK;

    for (int r8 = 0; r8 < 8; ++r8) {
        const int row = wv * 8 + r8;
        float vm = lg[row * 66 + lane] + bias[lane];
        float vals[TOPK];
        int   ids[TOPK];
        #pragma unroll
        for (int k = 0; k < TOPK; ++k) {
            float mv = vm;
            int   mi = lane;
            #pragma unroll
            for (int off = 32; off > 0; off >>= 1) {
                float ov = __shfl_xor(mv, off);
                int   oi = __shfl_xor(mi, off);
                if (ov > mv || (ov == mv && oi < mi)) { mv = ov; mi = oi; }
            }
            vals[k] = mv; ids[k] = mi;
            if (lane == mi) { vm = -INFINITY; atomicAdd(&hist[mi], 1); }
        }
        if (lane == 0) {
            const float m = vals[0];
            float e[TOPK];
            float ssum = 0.f;
            #pragma unroll
            for (int k = 0; k < TOPK; ++k) { e[k] = expf(vals[k] - m); ssum += e[k]; }
            const float inv = 1.0f / ssum;
            const size_t base = (size_t)(row0 + row) * TOPK;
            #pragma unroll
            for (int k = 0; k < TOPK; ++k) {
                out_scores[base + k] = e[k] * inv;
                out_idx[base + k]    = (float)ids[k];
            }
        }
    }

    __syncthreads();
    if (tid < NEXP) histws[bid * NEXP + tid] = hist[tid];
}

__global__ __launch_bounds__(512) void reduce_kernel(const int* __restrict__ histws,
                                                     float* __restrict__ counts) {
    __shared__ int partl[8][NEXP];
    const int t = threadIdx.x;
    const int e = t & 63, c = t >> 6;
    int sm = 0;
    for (int b = c; b < NBLK; b += 8) sm += histws[b * NEXP + e];
    partl[c][e] = sm;
    __syncthreads();
    if (t < NEXP) {
        int tot = 0;
        #pragma unroll
        for (int i = 0; i < 8; ++i) tot += partl[i][t];
        counts[t] = (float)tot;
    }
}

extern "C" void kernel_launch(void* const* d_in, const int* in_sizes, int n_in,
                              void* d_out, int out_size, void* d_ws, size_t ws_size,
                              hipStream_t stream) {
    const float* x    = (const float*)d_in[0];
    const float* w    = (const float*)d_in[1];
    const float* bias = (const float*)d_in[2];
    float* out = (float*)d_out;
    const int M = in_sizes[0] / DIM;   // 16384 rows

    unsigned int* wpack = (unsigned int*)d_ws;                      // 512 KB
    int* histws = (int*)((char*)d_ws + (1u << 20));                 // 64 KB
    float* out_counts = out + (size_t)2 * M * TOPK;

    prep_kernel<<<64, 256, 0, stream>>>(w, wpack);
    router_kernel<<<NBLK, NT, 0, stream>>>(x, wpack, bias, out, histws, M);
    reduce_kernel<<<1, 512, 0, stream>>>(histws, out_counts);
}

// Round 13
// 74.040 us; speedup vs baseline: 1.2801x; 1.1352x over previous
//
#include <hip/hip_runtime.h>
#include <math.h>

#define DIM   2048
#define NEXP  64
#define TOPK  8
#define BM    32
#define NT    512
#define NBLK  512          // M / BM

typedef __attribute__((ext_vector_type(8)))  short bf16x8;
typedef __attribute__((ext_vector_type(16))) float f32x16;

#define MFMA(A, B, C) __builtin_amdgcn_mfma_f32_32x32x16_bf16(A, B, C, 0, 0, 0)
#define AS_BF(v) (*(const bf16x8*)&(v))

typedef __attribute__((address_space(3))) unsigned int       lds_uint;
typedef __attribute__((address_space(1))) const unsigned int glb_uint;

#define STR2(x) #x
#define STR(x) STR2(x)
#define GL16(dst, p, off) \
    asm volatile("global_load_dwordx4 %0, %1, off offset:" STR(off) \
                 : "=v"(dst) : "v"(p) : "memory")

__device__ inline unsigned int bfpack(float a, float b) {
    unsigned int ua = __float_as_uint(a), ub = __float_as_uint(b);
    unsigned int lo = (ua + 0x7FFFu + ((ua >> 16) & 1u)) >> 16;
    unsigned int hi = (ub + 0x7FFFu + ((ub >> 16) & 1u)) & 0xFFFF0000u;
    return hi | lo;
}
__device__ inline void split2pair(float a, float b, unsigned int& h, unsigned int& m) {
    h = bfpack(a, b);
    float ra = a - __uint_as_float(h << 16);
    float rb = b - __uint_as_float(h & 0xFFFF0000u);
    m = bfpack(ra, rb);
}

// w[e][k] f32 -> byte = (T>>4)*65536 + (T&15)*4096 + (eh*2+term)*1024 + (kh*32+le)*16
//   T = k/16 global K16-tile index
__global__ __launch_bounds__(256) void prep_kernel(const float* __restrict__ w,
                                                   unsigned int* __restrict__ wpack) {
    const int u = blockIdx.x * 256 + threadIdx.x;   // 0..16383
    const int e = u >> 8, k8 = u & 255;
    const float4 v0 = *(const float4*)(w + (size_t)e * DIM + k8 * 8);
    const float4 v1 = *(const float4*)(w + (size_t)e * DIM + k8 * 8 + 4);
    unsigned int h[4], m[4];
    split2pair(v0.x, v0.y, h[0], m[0]);
    split2pair(v0.z, v0.w, h[1], m[1]);
    split2pair(v1.x, v1.y, h[2], m[2]);
    split2pair(v1.z, v1.w, h[3], m[3]);
    const int wv = k8 >> 5, t = (k8 >> 1) & 15, kh = k8 & 1;
    const int eh = e >> 5, le = e & 31;
    char* base = (char*)wpack + (size_t)wv * 65536 + t * 4096
               + (eh * 2) * 1024 + (kh * 32 + le) * 16;
    *(uint4*)(base)        = (uint4){h[0], h[1], h[2], h[3]};
    *(uint4*)(base + 1024) = (uint4){m[0], m[1], m[2], m[3]};
}

__global__ __launch_bounds__(NT, 4) void router_kernel(
    const float* __restrict__ x,
    const unsigned int* __restrict__ wpack,
    const float* __restrict__ bias,
    float* __restrict__ out,     // [M*8] scores | [M*8] idx(f32) | [64] counts(f32)
    int* __restrict__ histws,    // [NBLK][64]
    int M)
{
    // buffers: buf0 floats [0,8192), buf1 [8192,16384)  (64 KB)
    // epilogue lg[8*32][66] (67584 B) aliases; hist after
    __shared__ __align__(16) char smem[67584 + 256];
    float* smemf = (float*)smem;
    int* hist = (int*)(smem + 67584);

    const int tid  = threadIdx.x;
    const int bid  = blockIdx.x;
    const int swz  = (bid & 7) * (NBLK / 8) + (bid >> 3);   // bijective XCD swizzle
    const int row0 = swz * BM;
    if (tid < NEXP) hist[tid] = 0;

    const int wv   = tid >> 6;      // wave: K-slice within phase (tiles 2wv,2wv+1)
    const int lane = tid & 63;
    const int lr   = lane & 31;
    const int kh   = lane >> 5;

    // ---- x DMA mapping: granule G = j*512+tid -> [kt:16][rg:2][c:4][r15:16] ----
    const int rg  = (tid >> 6) & 1, r15 = tid & 15;
    const int c   = (tid >> 4) & 3;
    const float* xbase = x + (size_t)(row0 + rg * 16 + r15) * DIM
                       + (tid >> 7) * 16 + c * 4;
    float* dbase = smemf + tid * 4;

    // ---- w stream base: per phase ph, tile sub: wbase + ph*65536 (+4096 for sub=1) ----
    const char* wbase = (const char*)wpack + (2 * wv) * 4096 + lane * 16;

    // ---- compute read offset (floats) within a 512-float tile ----
    const int rdo = (lr >> 4) * 256 + kh * 128 + (lr & 15) * 4;
    const int cbase = (2 * wv) * 512 + rdo;

    f32x16 acc0 = {}, acc1 = {};
    uint4 w0h_A, w0m_A, w0H_A, w0M_A, w1h_A, w1m_A, w1H_A, w1M_A;
    uint4 w0h_B, w0m_B, w0H_B, w0M_B, w1h_B, w1m_B, w1H_B, w1M_B;

#define DMA4(BUFO, PH) do { \
        const float* s_ = xbase + (PH) * 256; \
        float* d_ = dbase + (BUFO); \
        __builtin_amdgcn_global_load_lds((glb_uint*)(const void*)(s_),       (lds_uint*)(void*)(d_),        16, 0, 0); \
        __builtin_amdgcn_global_load_lds((glb_uint*)(const void*)(s_ +  64), (lds_uint*)(void*)(d_ + 2048), 16, 0, 0); \
        __builtin_amdgcn_global_load_lds((glb_uint*)(const void*)(s_ + 128), (lds_uint*)(void*)(d_ + 4096), 16, 0, 0); \
        __builtin_amdgcn_global_load_lds((glb_uint*)(const void*)(s_ + 192), (lds_uint*)(void*)(d_ + 6144), 16, 0, 0); \
        asm volatile("" ::: "memory"); \
    } while (0)

#define WLD(S, PH) do { \
        const char* a_ = wbase + (PH) * 65536; \
        const char* b_ = a_ + 4096; \
        GL16(w0h_##S, a_, 0);    GL16(w0m_##S, a_, 1024); \
        GL16(w0H_##S, a_, 2048); GL16(w0M_##S, a_, 3072); \
        GL16(w1h_##S, b_, 0);    GL16(w1m_##S, b_, 1024); \
        GL16(w1H_##S, b_, 2048); GL16(w1M_##S, b_, 3072); \
    } while (0)

#define DOSPLIT(vlo, vhi, hv, mv) do { \
        unsigned int h_[4], m_[4]; \
        split2pair((vlo).x, (vlo).y, h_[0], m_[0]); \
        split2pair((vlo).z, (vlo).w, h_[1], m_[1]); \
        split2pair((vhi).x, (vhi).y, h_[2], m_[2]); \
        split2pair((vhi).z, (vhi).w, h_[3], m_[3]); \
        hv = (uint4){h_[0], h_[1], h_[2], h_[3]}; \
        mv = (uint4){m_[0], m_[1], m_[2], m_[3]}; \
    } while (0)

#define COMPUTE(S, BUFO) do { \
        const float* c0_ = smemf + (BUFO) + cbase; \
        float4 alo0_ = *(const float4*)(c0_); \
        float4 ahi0_ = *(const float4*)(c0_ + 64); \
        float4 alo1_ = *(const float4*)(c0_ + 512); \
        float4 ahi1_ = *(const float4*)(c0_ + 576); \
        uint4 ah_, am_; \
        DOSPLIT(alo0_, ahi0_, ah_, am_); \
        acc0 = MFMA(AS_BF(ah_), AS_BF(w0h_##S), acc0); \
        acc0 = MFMA(AS_BF(am_), AS_BF(w0h_##S), acc0); \
        acc0 = MFMA(AS_BF(ah_), AS_BF(w0m_##S), acc0); \
        acc1 = MFMA(AS_BF(ah_), AS_BF(w0H_##S), acc1); \
        acc1 = MFMA(AS_BF(am_), AS_BF(w0H_##S), acc1); \
        acc1 = MFMA(AS_BF(ah_), AS_BF(w0M_##S), acc1); \
        DOSPLIT(alo1_, ahi1_, ah_, am_); \
        acc0 = MFMA(AS_BF(ah_), AS_BF(w1h_##S), acc0); \
        acc0 = MFMA(AS_BF(am_), AS_BF(w1h_##S), acc0); \
        acc0 = MFMA(AS_BF(ah_), AS_BF(w1m_##S), acc0); \
        acc1 = MFMA(AS_BF(ah_), AS_BF(w1H_##S), acc1); \
        acc1 = MFMA(AS_BF(am_), AS_BF(w1H_##S), acc1); \
        acc1 = MFMA(AS_BF(ah_), AS_BF(w1M_##S), acc1); \
    } while (0)

#define VMW(N) do { asm volatile("s_waitcnt vmcnt(" STR(N) ")" ::: "memory"); \
                    __builtin_amdgcn_sched_barrier(0); } while (0)
#define BAR __builtin_amdgcn_s_barrier()

    // prologue: phase-0 x into buf0, phase-0 w into slot A
    DMA4(0, 0); WLD(A, 0);
    VMW(8); BAR;                       // DMAs done (w A still in flight)
    // steady phases: issue next (DMA+W) -> vmcnt(12) frees current w -> compute -> vmcnt(8) -> barrier
    DMA4(8192, 1); WLD(B, 1); VMW(12); COMPUTE(A, 0);    VMW(8); BAR;   // ph0
    DMA4(0,    2); WLD(A, 2); VMW(12); COMPUTE(B, 8192); VMW(8); BAR;   // ph1
    DMA4(8192, 3); WLD(B, 3); VMW(12); COMPUTE(A, 0);    VMW(8); BAR;   // ph2
    DMA4(0,    4); WLD(A, 4); VMW(12); COMPUTE(B, 8192); VMW(8); BAR;   // ph3
    DMA4(8192, 5); WLD(B, 5); VMW(12); COMPUTE(A, 0);    VMW(8); BAR;   // ph4
    DMA4(0,    6); WLD(A, 6); VMW(12); COMPUTE(B, 8192); VMW(8); BAR;   // ph5
    DMA4(8192, 7); WLD(B, 7); VMW(12); COMPUTE(A, 0);    VMW(8); BAR;   // ph6
    VMW(0); COMPUTE(B, 8192);                                           // ph7

#undef VMW
#undef COMPUTE
#undef DOSPLIT
#undef WLD
#undef DMA4

    __syncthreads();

    // ---- split-K-8 partials into lg[8*32][66] (aliases buffers) ----
    float* lgf = smemf;
    #pragma unroll
    for (int r = 0; r < 16; ++r) {
        const int rr = (r & 3) + 8 * (r >> 2) + 4 * kh;   // verified C-layout (m74/m101)
        lgf[(wv * 32 + rr) * 66 + lr]      = acc0[r];
        lgf[(wv * 32 + rr) * 66 + 32 + lr] = acc1[r];
    }
    __syncthreads();

    // ---- top-k + softmax + histogram (verified epilogue); wave wv: 4 rows ----
    float* out_scores = out;
    float* out_idx    = out + (size_t)M * TOPK;

    #pragma unroll
    for (int i = 0; i < 4; ++i) {
        const int row = wv * 4 + i;
        float vm = bias[lane];
        #pragma unroll
        for (int p = 0; p < 8; ++p) vm += lgf[(p * 32 + row) * 66 + lane];

        float vals[TOPK];
        int   ids[TOPK];
        #pragma unroll
        for (int k = 0; k < TOPK; ++k) {
            float mv = vm;
            int   mi = lane;
            #pragma unroll
            for (int off = 32; off > 0; off >>= 1) {
                float ov = __shfl_xor(mv, off);
                int   oi = __shfl_xor(mi, off);
                if (ov > mv || (ov == mv && oi < mi)) { mv = ov; mi = oi; }
            }
            vals[k] = mv; ids[k] = mi;
            if (lane == mi) { vm = -INFINITY; atomicAdd(&hist[mi], 1); }
        }
        if (lane == 0) {
            const float m = vals[0];
            float e[TOPK];
            float ssum = 0.f;
            #pragma unroll
            for (int k = 0; k < TOPK; ++k) { e[k] = expf(vals[k] - m); ssum += e[k]; }
            const float inv = 1.0f / ssum;
            const size_t base = (size_t)(row0 + row) * TOPK;
            #pragma unroll
            for (int k = 0; k < TOPK; ++k) {
                out_scores[base + k] = e[k] * inv;
                out_idx[base + k]    = (float)ids[k];
            }
        }
    }

    __syncthreads();
    if (tid < NEXP) histws[bid * NEXP + tid] = hist[tid];
}

__global__ __launch_bounds__(512) void reduce_kernel(const int* __restrict__ histws,
                                                     float* __restrict__ counts) {
    __shared__ int partl[8][NEXP];
    const int t = threadIdx.x;
    const int e = t & 63, c = t >> 6;
    int sm = 0;
    for (int b = c; b < NBLK; b += 8) sm += histws[b * NEXP + e];
    partl[c][e] = sm;
    __syncthreads();
    if (t < NEXP) {
        int tot = 0;
        #pragma unroll
        for (int i = 0; i < 8; ++i) tot += partl[i][t];
        counts[t] = (float)tot;
    }
}

extern "C" void kernel_launch(void* const* d_in, const int* in_sizes, int n_in,
                              void* d_out, int out_size, void* d_ws, size_t ws_size,
                              hipStream_t stream) {
    const float* x    = (const float*)d_in[0];
    const float* w    = (const float*)d_in[1];
    const float* bias = (const float*)d_in[2];
    float* out = (float*)d_out;
    const int M = in_sizes[0] / DIM;   // 16384 rows

    unsigned int* wpack = (unsigned int*)d_ws;                      // 512 KB
    int* histws = (int*)((char*)d_ws + (1u << 20));                 // 128 KB
    float* out_counts = out + (size_t)2 * M * TOPK;

    prep_kernel<<<64, 256, 0, stream>>>(w, wpack);
    router_kernel<<<NBLK, NT, 0, stream>>>(x, wpack, bias, out, histws, M);
    reduce_kernel<<<1, 512, 0, stream>>>(histws, out_counts);
}